// Round 12
// baseline (1202.472 us; speedup 1.0000x reference)
//
#include <hip/hip_runtime.h>

typedef float v2f __attribute__((ext_vector_type(2)));
typedef float v4f __attribute__((ext_vector_type(4)));

#define HID 30
#define TSTEPS 2048
#define BATCH 512
#define RING 64
#define L2E 1.4426950408889634f

__device__ __forceinline__ float fexp2(float x) { return __builtin_amdgcn_exp2f(x); }
__device__ __forceinline__ float frcp(float x)  { return __builtin_amdgcn_rcpf(x); }
__device__ __forceinline__ void  pinf(float& v) { asm("" : "+v"(v)); }
__device__ __forceinline__ void  pin2(v2f& v)  { asm("" : "+v"(v)); }

// Compile-time ordering fence: forbids IR reordering of LDS ops, emits NOTHING.
// DS ops from one wave complete in order at the LDS unit, so a counter write
// issued after data writes/reads is visible only after them — no lgkmcnt(0)
// drain needed (R11 lesson: the per-step drain pulled ~200 cyc of DS latency
// into every wave's critical path in ALL R4-R11 variants).
__device__ __forceinline__ void cfence() { asm volatile("" ::: "memory"); }

// acc += h * w (weight pinned to arch VGPR at use; h broadcast via SGPR)
__device__ __forceinline__ void fmac_sv(float& acc, float hs, float w) {
    asm("v_fmac_f32 %0, %1, %2" : "+v"(acc) : "s"(hs), "v"(w));
}

// acc(pair) += w(pair) * broadcast(src1.lo / src1.hi)  — R3-proven VOP3P forms.
__device__ __forceinline__ void pk_fma_lo(v2f& acc, v2f w, v2f hp) {
    asm("v_pk_fma_f32 %0, %1, %2, %0 op_sel:[0,0,0] op_sel_hi:[1,0,1]"
        : "+v"(acc) : "v"(w), "v"(hp));
}
__device__ __forceinline__ void pk_fma_hi(v2f& acc, v2f w, v2f hp) {
    asm("v_pk_fma_f32 %0, %1, %2, %0 op_sel:[0,1,0] op_sel_hi:[1,1,1]"
        : "+v"(acc) : "v"(w), "v"(hp));
}

// broadcast lane l of v to all lanes — VALU, result lands in SGPR
__device__ __forceinline__ float rl(float v, int l) {
    return __int_as_float(__builtin_amdgcn_readlane(__float_as_int(v), l));
}

// p from the other 32-lane half (lane ^ 32) via gfx950 VALU permlane32_swap.
__device__ __forceinline__ float other_half(float p, int h) {
#if __has_builtin(__builtin_amdgcn_permlane32_swap)
    auto r = __builtin_amdgcn_permlane32_swap(__float_as_uint(p), __float_as_uint(p),
                                              false, false);
    return __uint_as_float(h ? r[0] : r[1]);
#else
    return __shfl_xor(p, 32);
#endif
}

// Wave-wide sum via DPP. Valid in lane 63.
__device__ __forceinline__ float dpp_reduce63(float x) {
    x += __int_as_float(__builtin_amdgcn_update_dpp(0, __float_as_int(x), 0x111, 0xf, 0xf, true));
    x += __int_as_float(__builtin_amdgcn_update_dpp(0, __float_as_int(x), 0x112, 0xf, 0xf, true));
    x += __int_as_float(__builtin_amdgcn_update_dpp(0, __float_as_int(x), 0x114, 0xf, 0xf, true));
    x += __int_as_float(__builtin_amdgcn_update_dpp(0, __float_as_int(x), 0x118, 0xf, 0xf, true));
    x += __int_as_float(__builtin_amdgcn_update_dpp(0, __float_as_int(x), 0x142, 0xf, 0xf, true));
    x += __int_as_float(__builtin_amdgcn_update_dpp(0, __float_as_int(x), 0x143, 0xf, 0xf, true));
    return x;
}

// Block-per-batch, 3-wave decoupled producer/consumer LSTM (R10/R11 protocol),
// with NO per-step DS drains and pk_fma in the throughput stage:
//   wave0: layer1 (reg self-recurrence) -> ring_h1, publish prog[0] every 2.
//   wave1: partial W_ih2.h1 + b2 via v_pk_fma -> ring_p, publish every step.
//   wave2: W_hh2.h2 self-recurrence + gates + fc, publish prog[3] every 8.
__global__ __launch_bounds__(192, 1)
void lstm2_kernel(const float* __restrict__ x,
                  const float* __restrict__ w_ih1, const float* __restrict__ w_hh1,
                  const float* __restrict__ b_ih1, const float* __restrict__ b_hh1,
                  const float* __restrict__ w_ih2, const float* __restrict__ w_hh2,
                  const float* __restrict__ b_ih2, const float* __restrict__ b_hh2,
                  const float* __restrict__ w_fc,  const float* __restrict__ b_fc,
                  float* __restrict__ out)
{
    const int b    = blockIdx.x;
    const int tid  = threadIdx.x;
    const int wave = tid >> 6;
    const int lane = tid & 63;
    const int k    = lane & 31;
    const int h    = lane >> 5;
    const int kk   = (k < HID) ? k : (HID - 1);  // lanes k=30,31 duplicate unit 29
    const int rowA = h * 30 + kk;                // h0: i-row, h1: f-row
    const int rowB = 60 + h * 30 + kk;           // h0: g-row, h1: o-row

    __shared__ __align__(16) float ring_h1[RING][32];   // h1(t) at slot t%64 (30 used)
    __shared__ __align__(16) float ring_p[RING][128];   // partial v2f per lane
    __shared__ int prog[4];  // 0: h1 shipped, 1: h1 consumed, 2: p shipped, 3: p consumed
    for (int i = tid; i < RING; i += 192) { ring_h1[i][30] = 0.0f; ring_h1[i][31] = 0.0f; }
    if (tid < 4) prog[tid] = -1;
    __syncthreads();   // once, outside the loop
    volatile int* vp = (volatile int*)prog;

    // ---- per-wave weights ----
    // wave0: wr0/wr1 = whh1 rowA/rowB (scalars, fmac_sv)
    // wave1: wp[j] = {wih2 rowA[j], wih2 rowB[j]} pairs (pk_fma)
    // wave2: wr0/wr1 = whh2 rowA/rowB (scalars, fmac_sv)
    float wr0[30], wr1[30];
    v2f   wp[30];
    float bb0 = 0.0f, bb1 = 0.0f;
    float wxa = 0.0f, wxb = 0.0f;
    float wfck = 0.0f;
    if (wave == 0) {
#pragma unroll
        for (int j = 0; j < 30; ++j) {
            wr0[j] = w_hh1[rowA * HID + j];
            wr1[j] = w_hh1[rowB * HID + j];
        }
        bb0 = b_ih1[rowA] + b_hh1[rowA];
        bb1 = b_ih1[rowB] + b_hh1[rowB];
        wxa = w_ih1[rowA];
        wxb = w_ih1[rowB];
#pragma unroll
        for (int j = 0; j < 30; ++j) { pinf(wr0[j]); pinf(wr1[j]); }
    } else if (wave == 1) {
#pragma unroll
        for (int j = 0; j < 30; ++j)
            wp[j] = (v2f){w_ih2[rowA * HID + j], w_ih2[rowB * HID + j]};
        bb0 = b_ih2[rowA] + b_hh2[rowA];
        bb1 = b_ih2[rowB] + b_hh2[rowB];
#pragma unroll
        for (int j = 0; j < 30; ++j) pin2(wp[j]);
    } else {
#pragma unroll
        for (int j = 0; j < 30; ++j) {
            wr0[j] = w_hh2[rowA * HID + j];
            wr1[j] = w_hh2[rowB * HID + j];
        }
        wfck = (h && k < HID) ? w_fc[k] : 0.0f;
#pragma unroll
        for (int j = 0; j < 30; ++j) { pinf(wr0[j]); pinf(wr1[j]); }
    }
    pinf(bb0); pinf(bb1); pinf(wxa); pinf(wxb); pinf(wfck);
    const float bfc = __int_as_float(__builtin_amdgcn_readfirstlane(__float_as_int(b_fc[0])));

    // gate-y activation constants: h0 -> tanh (g), h1 -> sigmoid (o)
    const float cy = h ? (-L2E) : (-2.0f * L2E);
    const float my = h ? 1.0f : 2.0f;
    const float ay = h ? 0.0f : -1.0f;

    float hh  = 0.0f;   // wave0: h1[kk] (h=1 half); wave2: h2[kk]
    float cst = 0.0f;   // wave0: c1;  wave2: c2
    const float* xp   = x   + (size_t)b * TSTEPS;
    float*       outp = out + (size_t)b * TSTEPS;

    if (wave == 0) {
        // =================== free-running producer: layer 1 ===================
        float xv_cur = xp[lane];
        float xv_nxt = xp[64 + lane];
        for (int tt = 0; tt < TSTEPS; ++tt) {
            if ((tt & 31) == 0) {   // WAR: slots tt..tt+31 overwrite h1(tt-64..tt-33)
                while (vp[1] < tt - 33) __builtin_amdgcn_s_sleep(2);
                cfence();
            }
            if ((tt & 63) == 0 && tt) {
                xv_cur = xv_nxt;                           // loaded 64 iters ago
                if (tt + 64 < TSTEPS) xv_nxt = xp[tt + 64 + lane];
            }
            const float xt = rl(xv_cur, tt & 63);
            float a0 = bb0, a1 = 0.0f;                     // rowA pre (i/f)
            float g0 = bb1, g1 = 0.0f;                     // rowB pre (g/o)
            fmac_sv(a0, xt, wxa);
            fmac_sv(g0, xt, wxb);
#pragma unroll
            for (int j = 0; j < 30; j += 2) {
                const float hj0 = rl(hh, 32 + j);          // h1(tt-1)[j]
                const float hj1 = rl(hh, 33 + j);
                fmac_sv(a0, hj0, wr0[j]);
                fmac_sv(g0, hj0, wr1[j]);
                fmac_sv(a1, hj1, wr0[j + 1]);
                fmac_sv(g1, hj1, wr1[j + 1]);
            }
            const float preA = a0 + a1, preB = g0 + g1;
            const float gx = frcp(1.0f + fexp2(preA * (-L2E)));           // i / f
            const float gy = fmaf(frcp(1.0f + fexp2(preB * cy)), my, ay); // g / o
            const float p  = gx * gy;
            const float px = other_half(p, h);
            cst = fmaf(gx, cst, px);                       // c1
            const float tc = fmaf(2.0f, frcp(1.0f + fexp2(cst * (-2.0f * L2E))), -1.0f);
            hh = gy * tc;                                  // h1(tt)[kk] in h=1 half
            if (h) ring_h1[tt & (RING - 1)][kk] = hh;      // ship h1(tt)
            cfence();                                      // order: data before counter
            if ((tt & 1) && lane == 0) vp[0] = tt;         // DS in-order => visible after data
        }
    } else if (wave == 1) {
        // ======== throughput stage (no recurrence): W_ih2.h1 + b2, pk_fma ========
        for (int s = 0; s < TSTEPS; ++s) {
            if ((s & 7) == 0) {
                while (vp[0] < s + 7) __builtin_amdgcn_s_sleep(1);   // h1 avail
                while (vp[3] < s - 57) __builtin_amdgcn_s_sleep(1);  // WAR on ring_p
                cfence();
            }
            const v4f* hc4 = (const v4f*)ring_h1[s & (RING - 1)];
            v2f acc0 = (v2f){bb0, bb1};
            v2f acc1 = (v2f){0.0f, 0.0f};
            v2f acc2 = (v2f){0.0f, 0.0f};
            v2f acc3 = (v2f){0.0f, 0.0f};
#pragma unroll
            for (int c = 0; c < 7; ++c) {                  // j = 0..27
                const v4f hc = hc4[c];                     // broadcast read
                v2f lo = hc.xy, hi = hc.zw;
                pk_fma_lo(acc0, wp[4 * c + 0], lo);
                pk_fma_hi(acc1, wp[4 * c + 1], lo);
                pk_fma_lo(acc2, wp[4 * c + 2], hi);
                pk_fma_hi(acc3, wp[4 * c + 3], hi);
            }
            {                                              // tail j = 28,29
                const v2f tl = ((const v2f*)ring_h1[s & (RING - 1)])[14];
                pk_fma_lo(acc0, wp[28], tl);
                pk_fma_hi(acc1, wp[29], tl);
            }
            const v2f pr = (acc0 + acc1) + (acc2 + acc3);
            ((v2f*)ring_p[s & (RING - 1)])[lane] = pr;
            cfence();                                      // data before counter
            if (lane == 0) {
                vp[2] = s;                                 // partial shipped
                if ((s & 7) == 7) vp[1] = s;               // h1 consumed (reads precede)
            }
        }
    } else {
        // ============ consumer: W_hh2.h2 self-recurrence + gates + fc ============
        for (int s = 0; s < TSTEPS; ++s) {
            if ((s & 7) == 0) {
                while (vp[2] < s + 7) __builtin_amdgcn_s_sleep(1);   // partials avail
                cfence();
            }
            const v2f part = ((const v2f*)ring_p[s & (RING - 1)])[lane];
            float dA0 = 0.0f, dA1 = 0.0f, dB0 = 0.0f, dB1 = 0.0f;
#pragma unroll
            for (int j = 0; j < 30; j += 2) {
                const float hj0 = rl(hh, 32 + j);          // h2(s-1)[j]
                const float hj1 = rl(hh, 33 + j);
                fmac_sv(dA0, hj0, wr0[j]);
                fmac_sv(dB0, hj0, wr1[j]);
                fmac_sv(dA1, hj1, wr0[j + 1]);
                fmac_sv(dB1, hj1, wr1[j + 1]);
            }
            const float preA = (dA0 + dA1) + part.x;
            const float preB = (dB0 + dB1) + part.y;
            const float gx = frcp(1.0f + fexp2(preA * (-L2E)));
            const float gy = fmaf(frcp(1.0f + fexp2(preB * cy)), my, ay);
            const float p  = gx * gy;
            const float px = other_half(p, h);
            cst = fmaf(gx, cst, px);                       // c2
            const float tc = fmaf(2.0f, frcp(1.0f + fexp2(cst * (-2.0f * L2E))), -1.0f);
            hh = gy * tc;                                  // h2(s)[kk] in h=1 half
            const float sum = dpp_reduce63(wfck * hh);     // fc head
            if (lane == 63) outp[s] = sum + bfc;           // store stays in flight
            cfence();                                      // reads before counter
            if ((s & 7) == 7 && lane == 0) vp[3] = s;      // consumption publish
        }
    }
}

extern "C" void kernel_launch(void* const* d_in, const int* in_sizes, int n_in,
                              void* d_out, int out_size, void* d_ws, size_t ws_size,
                              hipStream_t stream)
{
    const float* x     = (const float*)d_in[0];
    const float* w_ih1 = (const float*)d_in[1];
    const float* w_hh1 = (const float*)d_in[2];
    const float* b_ih1 = (const float*)d_in[3];
    const float* b_hh1 = (const float*)d_in[4];
    const float* w_ih2 = (const float*)d_in[5];
    const float* w_hh2 = (const float*)d_in[6];
    const float* b_ih2 = (const float*)d_in[7];
    const float* b_hh2 = (const float*)d_in[8];
    const float* w_fc  = (const float*)d_in[9];
    const float* b_fc  = (const float*)d_in[10];
    float* out = (float*)d_out;

    lstm2_kernel<<<BATCH, 192, 0, stream>>>(x, w_ih1, w_hh1, b_ih1, b_hh1,
                                            w_ih2, w_hh2, b_ih2, b_hh2,
                                            w_fc, b_fc, out);
}

// Round 13
// 1159.815 us; speedup vs baseline: 1.0368x; 1.0368x over previous
//
#include <hip/hip_runtime.h>

typedef float v2f __attribute__((ext_vector_type(2)));
typedef float v4f __attribute__((ext_vector_type(4)));

#define HID 30
#define TSTEPS 2048
#define BATCH 512
#define RING 64
#define L2E 1.4426950408889634f

__device__ __forceinline__ float fexp2(float x) { return __builtin_amdgcn_exp2f(x); }
__device__ __forceinline__ float frcp(float x)  { return __builtin_amdgcn_rcpf(x); }
__device__ __forceinline__ void  pinf(float& v) { asm("" : "+v"(v)); }
__device__ __forceinline__ void  pin2(v2f& v)  { asm("" : "+v"(v)); }

// Compile-time ordering fence (emits nothing). DS ops of one wave complete in
// order at the LDS unit -> counter write issued after data ops is visible after.
__device__ __forceinline__ void cfence() { asm volatile("" ::: "memory"); }

// acc(pair) += w(pair) * broadcast(src1.lo / src1.hi)  — R3-proven VOP3P forms.
__device__ __forceinline__ void pk_fma_lo(v2f& acc, v2f w, v2f hp) {
    asm("v_pk_fma_f32 %0, %1, %2, %0 op_sel:[0,0,0] op_sel_hi:[1,0,1]"
        : "+v"(acc) : "v"(w), "v"(hp));
}
__device__ __forceinline__ void pk_fma_hi(v2f& acc, v2f w, v2f hp) {
    asm("v_pk_fma_f32 %0, %1, %2, %0 op_sel:[0,1,0] op_sel_hi:[1,1,1]"
        : "+v"(acc) : "v"(w), "v"(hp));
}

// broadcast lane l of v to all lanes — VALU, result lands in SGPR
__device__ __forceinline__ float rl(float v, int l) {
    return __int_as_float(__builtin_amdgcn_readlane(__float_as_int(v), l));
}

// p from the other 32-lane half (lane ^ 32) via gfx950 VALU permlane32_swap.
__device__ __forceinline__ float other_half(float p, int h) {
#if __has_builtin(__builtin_amdgcn_permlane32_swap)
    auto r = __builtin_amdgcn_permlane32_swap(__float_as_uint(p), __float_as_uint(p),
                                              false, false);
    return __uint_as_float(h ? r[0] : r[1]);
#else
    return __shfl_xor(p, 32);
#endif
}

// Wave-wide sum via DPP. Valid in lane 63.
__device__ __forceinline__ float dpp_reduce63(float x) {
    x += __int_as_float(__builtin_amdgcn_update_dpp(0, __float_as_int(x), 0x111, 0xf, 0xf, true));
    x += __int_as_float(__builtin_amdgcn_update_dpp(0, __float_as_int(x), 0x112, 0xf, 0xf, true));
    x += __int_as_float(__builtin_amdgcn_update_dpp(0, __float_as_int(x), 0x114, 0xf, 0xf, true));
    x += __int_as_float(__builtin_amdgcn_update_dpp(0, __float_as_int(x), 0x118, 0xf, 0xf, true));
    x += __int_as_float(__builtin_amdgcn_update_dpp(0, __float_as_int(x), 0x142, 0xf, 0xf, true));
    x += __int_as_float(__builtin_amdgcn_update_dpp(0, __float_as_int(x), 0x143, 0xf, 0xf, true));
    return x;
}

// Block-per-batch, 3-wave decoupled ring LSTM. R13 change: each wave's weights
// are declared+loaded+pinned+USED entirely inside its own branch, so no weight
// live-range crosses a branch boundary. Cross-round evidence (R4..R12): the
// allocator spills to AGPR/scratch when the live set at the load/use midpoint
// exceeds ~64 floats (R12: 180 -> VGPR 68); keeps ~60 resident (R6/R8: VGPR 112).
__global__ __launch_bounds__(192, 1)
void lstm2_kernel(const float* __restrict__ x,
                  const float* __restrict__ w_ih1, const float* __restrict__ w_hh1,
                  const float* __restrict__ b_ih1, const float* __restrict__ b_hh1,
                  const float* __restrict__ w_ih2, const float* __restrict__ w_hh2,
                  const float* __restrict__ b_ih2, const float* __restrict__ b_hh2,
                  const float* __restrict__ w_fc,  const float* __restrict__ b_fc,
                  float* __restrict__ out)
{
    const int b    = blockIdx.x;
    const int tid  = threadIdx.x;
    const int wave = tid >> 6;
    const int lane = tid & 63;
    const int k    = lane & 31;
    const int h    = lane >> 5;
    const int kk   = (k < HID) ? k : (HID - 1);  // lanes k=30,31 duplicate unit 29
    const int rowA = h * 30 + kk;                // h0: i-row, h1: f-row
    const int rowB = 60 + h * 30 + kk;           // h0: g-row, h1: o-row

    __shared__ __align__(16) float ring_h1[RING][32];   // h1(t) at slot t%64 (30 used)
    __shared__ __align__(16) float ring_p[RING][128];   // partial v2f per lane
    __shared__ int prog[4];  // 0: h1 shipped, 1: h1 consumed, 2: p shipped, 3: p consumed
    for (int i = tid; i < RING; i += 192) { ring_h1[i][30] = 0.0f; ring_h1[i][31] = 0.0f; }
    if (tid < 4) prog[tid] = -1;
    __syncthreads();   // once, outside the loops
    volatile int* vp = (volatile int*)prog;

    const float bfc = __int_as_float(__builtin_amdgcn_readfirstlane(__float_as_int(b_fc[0])));
    // gate-y activation constants: h0 -> tanh (g), h1 -> sigmoid (o)
    const float cy = h ? (-L2E) : (-2.0f * L2E);
    const float my = h ? 1.0f : 2.0f;
    const float ay = h ? 0.0f : -1.0f;
    const float* xp   = x   + (size_t)b * TSTEPS;
    float*       outp = out + (size_t)b * TSTEPS;

    if (wave == 0) {
        // ========== free-running producer: layer 1 (self-contained branch) ==========
        float wr0[30], wr1[30];
#pragma unroll
        for (int j = 0; j < 30; ++j) {
            wr0[j] = w_hh1[rowA * HID + j];
            wr1[j] = w_hh1[rowB * HID + j];
        }
        float bb0 = b_ih1[rowA] + b_hh1[rowA];
        float bb1 = b_ih1[rowB] + b_hh1[rowB];
        float wxa = w_ih1[rowA];
        float wxb = w_ih1[rowB];
#pragma unroll
        for (int j = 0; j < 30; ++j) { pinf(wr0[j]); pinf(wr1[j]); }
        pinf(bb0); pinf(bb1); pinf(wxa); pinf(wxb);

        float hh = 0.0f, cst = 0.0f;
        float xv_cur = xp[lane];
        float xv_nxt = xp[64 + lane];
        for (int tt = 0; tt < TSTEPS; ++tt) {
            if ((tt & 31) == 0) {   // WAR: slots tt..tt+31 overwrite h1(tt-64..tt-33)
                while (vp[1] < tt - 33) __builtin_amdgcn_s_sleep(2);
                cfence();
            }
            if ((tt & 63) == 0 && tt) {
                xv_cur = xv_nxt;                           // loaded 64 iters ago
                if (tt + 64 < TSTEPS) xv_nxt = xp[tt + 64 + lane];
            }
            const float xt = rl(xv_cur, tt & 63);
            float a0 = fmaf(xt, wxa, bb0), a1 = 0.0f;      // rowA pre (i/f)
            float g0 = fmaf(xt, wxb, bb1), g1 = 0.0f;      // rowB pre (g/o)
#pragma unroll
            for (int j = 0; j < 30; j += 2) {
                const float hj0 = rl(hh, 32 + j);          // h1(tt-1)[j]
                const float hj1 = rl(hh, 33 + j);
                a0 = fmaf(wr0[j],     hj0, a0);
                g0 = fmaf(wr1[j],     hj0, g0);
                a1 = fmaf(wr0[j + 1], hj1, a1);
                g1 = fmaf(wr1[j + 1], hj1, g1);
            }
            const float preA = a0 + a1, preB = g0 + g1;
            const float gx = frcp(1.0f + fexp2(preA * (-L2E)));           // i / f
            const float gy = fmaf(frcp(1.0f + fexp2(preB * cy)), my, ay); // g / o
            const float p  = gx * gy;
            const float px = other_half(p, h);
            cst = fmaf(gx, cst, px);                       // c1
            const float tc = fmaf(2.0f, frcp(1.0f + fexp2(cst * (-2.0f * L2E))), -1.0f);
            hh = gy * tc;                                  // h1(tt)[kk] in h=1 half
            if (h) ring_h1[tt & (RING - 1)][kk] = hh;      // ship h1(tt)
            cfence();                                      // data before counter
            if ((tt & 1) && lane == 0) vp[0] = tt;
        }
    } else if (wave == 1) {
        // ===== throughput stage (no recurrence): W_ih2.h1 + b2 (self-contained) =====
        v2f wp[30];
#pragma unroll
        for (int j = 0; j < 30; ++j)
            wp[j] = (v2f){w_ih2[rowA * HID + j], w_ih2[rowB * HID + j]};
        float bb0 = b_ih2[rowA] + b_hh2[rowA];
        float bb1 = b_ih2[rowB] + b_hh2[rowB];
#pragma unroll
        for (int j = 0; j < 30; ++j) pin2(wp[j]);
        pinf(bb0); pinf(bb1);

        for (int s = 0; s < TSTEPS; ++s) {
            if ((s & 7) == 0) {
                while (vp[0] < s + 7) __builtin_amdgcn_s_sleep(1);   // h1 avail
                while (vp[3] < s - 57) __builtin_amdgcn_s_sleep(1);  // WAR on ring_p
                cfence();
            }
            const v4f* hc4 = (const v4f*)ring_h1[s & (RING - 1)];
            v2f acc0 = (v2f){bb0, bb1};
            v2f acc1 = (v2f){0.0f, 0.0f};
            v2f acc2 = (v2f){0.0f, 0.0f};
            v2f acc3 = (v2f){0.0f, 0.0f};
#pragma unroll
            for (int c = 0; c < 7; ++c) {                  // j = 0..27
                const v4f hc = hc4[c];                     // broadcast read
                v2f lo = hc.xy, hi = hc.zw;
                pk_fma_lo(acc0, wp[4 * c + 0], lo);
                pk_fma_hi(acc1, wp[4 * c + 1], lo);
                pk_fma_lo(acc2, wp[4 * c + 2], hi);
                pk_fma_hi(acc3, wp[4 * c + 3], hi);
            }
            {                                              // tail j = 28,29
                const v2f tl = ((const v2f*)ring_h1[s & (RING - 1)])[14];
                pk_fma_lo(acc0, wp[28], tl);
                pk_fma_hi(acc1, wp[29], tl);
            }
            const v2f pr = (acc0 + acc1) + (acc2 + acc3);
            ((v2f*)ring_p[s & (RING - 1)])[lane] = pr;
            cfence();                                      // data before counter
            if (lane == 0) {
                vp[2] = s;                                 // partial shipped
                if ((s & 7) == 7) vp[1] = s;               // h1 consumed
            }
        }
    } else {
        // ==== consumer: W_hh2.h2 self-recurrence + gates + fc (self-contained) ====
        float wr0[30], wr1[30];
#pragma unroll
        for (int j = 0; j < 30; ++j) {
            wr0[j] = w_hh2[rowA * HID + j];
            wr1[j] = w_hh2[rowB * HID + j];
        }
        float wfck = (h && k < HID) ? w_fc[k] : 0.0f;
#pragma unroll
        for (int j = 0; j < 30; ++j) { pinf(wr0[j]); pinf(wr1[j]); }
        pinf(wfck);

        float hh = 0.0f, cst = 0.0f;
        for (int s = 0; s < TSTEPS; ++s) {
            if ((s & 7) == 0) {
                while (vp[2] < s + 7) __builtin_amdgcn_s_sleep(1);   // partials avail
                cfence();
            }
            const v2f part = ((const v2f*)ring_p[s & (RING - 1)])[lane];
            float dA0 = 0.0f, dA1 = 0.0f, dB0 = 0.0f, dB1 = 0.0f;
#pragma unroll
            for (int j = 0; j < 30; j += 2) {
                const float hj0 = rl(hh, 32 + j);          // h2(s-1)[j]
                const float hj1 = rl(hh, 33 + j);
                dA0 = fmaf(wr0[j],     hj0, dA0);
                dB0 = fmaf(wr1[j],     hj0, dB0);
                dA1 = fmaf(wr0[j + 1], hj1, dA1);
                dB1 = fmaf(wr1[j + 1], hj1, dB1);
            }
            const float preA = (dA0 + dA1) + part.x;
            const float preB = (dB0 + dB1) + part.y;
            const float gx = frcp(1.0f + fexp2(preA * (-L2E)));
            const float gy = fmaf(frcp(1.0f + fexp2(preB * cy)), my, ay);
            const float p  = gx * gy;
            const float px = other_half(p, h);
            cst = fmaf(gx, cst, px);                       // c2
            const float tc = fmaf(2.0f, frcp(1.0f + fexp2(cst * (-2.0f * L2E))), -1.0f);
            hh = gy * tc;                                  // h2(s)[kk] in h=1 half
            const float sum = dpp_reduce63(wfck * hh);     // fc head
            if (lane == 63) outp[s] = sum + bfc;           // store stays in flight
            cfence();                                      // reads before counter
            if ((s & 7) == 7 && lane == 0) vp[3] = s;
        }
    }
}

extern "C" void kernel_launch(void* const* d_in, const int* in_sizes, int n_in,
                              void* d_out, int out_size, void* d_ws, size_t ws_size,
                              hipStream_t stream)
{
    const float* x     = (const float*)d_in[0];
    const float* w_ih1 = (const float*)d_in[1];
    const float* w_hh1 = (const float*)d_in[2];
    const float* b_ih1 = (const float*)d_in[3];
    const float* b_hh1 = (const float*)d_in[4];
    const float* w_ih2 = (const float*)d_in[5];
    const float* w_hh2 = (const float*)d_in[6];
    const float* b_ih2 = (const float*)d_in[7];
    const float* b_hh2 = (const float*)d_in[8];
    const float* w_fc  = (const float*)d_in[9];
    const float* b_fc  = (const float*)d_in[10];
    float* out = (float*)d_out;

    lstm2_kernel<<<BATCH, 192, 0, stream>>>(x, w_ih1, w_hh1, b_ih1, b_hh1,
                                            w_ih2, w_hh2, b_ih2, b_hh2,
                                            w_fc, b_fc, out);
}